// Round 8
// baseline (323.891 us; speedup 1.0000x reference)
//
#include <hip/hip_runtime.h>
#include <hip/hip_bf16.h>

typedef __bf16 bf16_t;
typedef __bf16 bf16x8 __attribute__((ext_vector_type(8)));
typedef __bf16 bf16x4 __attribute__((ext_vector_type(4)));
typedef __bf16 bf16x2 __attribute__((ext_vector_type(2)));
typedef float  f32x4  __attribute__((ext_vector_type(4)));

#define S_LEN 4096
#define NH    8
#define DH    64
#define DE    512

// ---------------------------------------------------------------------------
// GEMM tile params (both projection GEMMs)
// ---------------------------------------------------------------------------
#define BM 128
#define BN 128
#define BK 32
#define LDP 40

static __device__ __forceinline__ void stage16_f32(bf16_t* dst, const float* src) {
    const float4 v0 = *reinterpret_cast<const float4*>(src + 0);
    const float4 v1 = *reinterpret_cast<const float4*>(src + 4);
    const float4 v2 = *reinterpret_cast<const float4*>(src + 8);
    const float4 v3 = *reinterpret_cast<const float4*>(src + 12);
    bf16x8 lo, hi;
    lo[0]=(bf16_t)v0.x; lo[1]=(bf16_t)v0.y; lo[2]=(bf16_t)v0.z; lo[3]=(bf16_t)v0.w;
    lo[4]=(bf16_t)v1.x; lo[5]=(bf16_t)v1.y; lo[6]=(bf16_t)v1.z; lo[7]=(bf16_t)v1.w;
    hi[0]=(bf16_t)v2.x; hi[1]=(bf16_t)v2.y; hi[2]=(bf16_t)v2.z; hi[3]=(bf16_t)v2.w;
    hi[4]=(bf16_t)v3.x; hi[5]=(bf16_t)v3.y; hi[6]=(bf16_t)v3.z; hi[7]=(bf16_t)v3.w;
    *reinterpret_cast<bf16x8*>(dst + 0) = lo;
    *reinterpret_cast<bf16x8*>(dst + 8) = hi;
}

// ---------------------------------------------------------------------------
// Kernel 1: qkv = x @ w_in^T + b_in ; scatter to Q [h][s][64], K [h][s][64],
//           V^T [h][64][s]   (all bf16)
// ---------------------------------------------------------------------------
__global__ __launch_bounds__(256) void qkv_gemm(
    const float* __restrict__ X,
    const float* __restrict__ Win,
    const float* __restrict__ bin,
    bf16_t* __restrict__ qw,
    bf16_t* __restrict__ kw,
    bf16_t* __restrict__ vtw)
{
    __shared__ bf16_t As[BM * LDP];
    __shared__ bf16_t Bs[BN * LDP];

    const int tid  = threadIdx.x;
    const int lane = tid & 63;
    const int w    = tid >> 6;
    const int wr   = w >> 1, wc = w & 1;
    const int row0 = blockIdx.y * BM;
    const int col0 = blockIdx.x * BN;

    const int fr = lane & 15;
    const int fo = (lane >> 4) * 8;
    const int cr = (lane >> 4) * 4;

    const int sr = tid >> 1;
    const int sc = (tid & 1) * 16;

    f32x4 acc[4][4] = {};

    for (int k0 = 0; k0 < DE; k0 += BK) {
        stage16_f32(As + sr * LDP + sc, X   + (row0 + sr) * DE + k0 + sc);
        stage16_f32(Bs + sr * LDP + sc, Win + (col0 + sr) * DE + k0 + sc);
        __syncthreads();

        bf16x8 af[4], bf[4];
        #pragma unroll
        for (int m = 0; m < 4; ++m)
            af[m] = *reinterpret_cast<const bf16x8*>(As + (wr * 64 + m * 16 + fr) * LDP + fo);
        #pragma unroll
        for (int n = 0; n < 4; ++n)
            bf[n] = *reinterpret_cast<const bf16x8*>(Bs + (wc * 64 + n * 16 + fr) * LDP + fo);
        #pragma unroll
        for (int m = 0; m < 4; ++m)
            #pragma unroll
            for (int n = 0; n < 4; ++n)
                acc[m][n] = __builtin_amdgcn_mfma_f32_16x16x32_bf16(af[m], bf[n], acc[m][n], 0, 0, 0);
        __syncthreads();
    }

    #pragma unroll
    for (int m = 0; m < 4; ++m) {
        #pragma unroll
        for (int n = 0; n < 4; ++n) {
            const int col = col0 + wc * 64 + n * 16 + fr;
            const float b = bin[col];
            const int part = col >> 9;
            const int cd   = col & 511;
            const int h    = cd >> 6;
            const int d    = cd & 63;
            #pragma unroll
            for (int r = 0; r < 4; ++r) {
                const int row = row0 + wr * 64 + m * 16 + cr + r;
                const float v = acc[m][n][r] + b;
                const bf16_t bv = (bf16_t)v;
                if (part == 0)      qw [(h * S_LEN + row) * DH + d] = bv;
                else if (part == 1) kw [(h * S_LEN + row) * DH + d] = bv;
                else                vtw[(h * DH + d) * S_LEN + row] = bv;
            }
        }
    }
}

// ---------------------------------------------------------------------------
// Kernel 2: attention, softmax over HEADS axis.
// 1024-thread block = 16 waves: wave = (head h, q-half qh), each owns 16
// queries of the 32-query tile. KS-way key split. Double-buffered e-LDS
// (64 KB) -> 2 barriers/tile; 2 blocks/CU = 32 waves/CU (100% occupancy;
// r7 was 16/32, latency-bound at VALUBusy 37%).
//
// Transposed QK^T: mfma(K,Q) -> D[col=q (lane&15), row=k (fog*4+r)], so
// each lane holds 4 CONSECUTIVE k for fixed q -> e-store is one b64 write
// per kf (vs 16 scalar b16 in r7). LDS layout [buf][h][q][64k] with 16B
// block swizzle p' = p ^ (fr&7); PV b128 reads land conflict-free per
// 16-lane quarter. Per-wave regs: aq 8 + kfrag 8 + o 16 (acc) + temps
// ~= 55 total <= 64 -> 8 waves/SIMD fits.
// ---------------------------------------------------------------------------
template<int KS>
__global__ __launch_bounds__(1024, 2) void attn_kernel(
    const bf16_t* __restrict__ qw,    // [h][s][64]
    const bf16_t* __restrict__ kw,    // [h][s][64]
    const bf16_t* __restrict__ vtw,   // [h][64][s]
    const int*    __restrict__ causal_p,
    bf16_t* __restrict__ part)        // [KS][s][512] partial outputs
{
    constexpr int QT = 32;
    constexpr int NT = (S_LEN / KS) / 64;
    constexpr int KSH = (KS == 4) ? 2 : (KS == 2 ? 1 : 0);

    __shared__ bf16_t e_lds[2][NH][QT][64];   // 64 KB

    const int tid  = threadIdx.x;
    const int lane = tid & 63;
    const int wid  = tid >> 6;          // 0..15
    const int h    = wid & 7;           // head
    const int qh   = wid >> 3;          // q-half (0,1)
    const int kc   = blockIdx.x & (KS - 1);
    const int q0   = (blockIdx.x >> KSH) * QT;
    const int kbase = kc * (S_LEN / KS);
    const int causal = causal_p[0];

    const int fr  = lane & 15;
    const int fog = lane >> 4;
    const int fo  = fog * 8;
    const int cr  = fog * 4;
    const int qw0 = qh * 16;            // wave's q offset within tile

    // Q fragments as the MFMA *B*-operand (col = q = fr, elems = d)
    bf16x8 aq0, aq1;
    {
        const bf16_t* qb = qw + ((size_t)(h * S_LEN) + q0 + qw0 + fr) * DH;
        aq0 = *reinterpret_cast<const bf16x8*>(qb + fo);
        aq1 = *reinterpret_cast<const bf16x8*>(qb + 32 + fo);
    }

    f32x4 o[4] = {};   // output accumulators (acc side)

    for (int t = 0; t < NT; ++t) {
        const int kg = kbase + t * 64;
        bf16_t* ebuf = &e_lds[t & 1][h][0][0];

        // ---- transposed QK^T + exp: D[k][q], one b64 e-write per kf ----
        #pragma unroll 1
        for (int kf = 0; kf < 4; ++kf) {
            const bf16_t* kb = kw + ((size_t)(h * S_LEN) + kg + kf * 16 + fr) * DH;
            const bf16x8 k0v = *reinterpret_cast<const bf16x8*>(kb + fo);
            const bf16x8 k1v = *reinterpret_cast<const bf16x8*>(kb + 32 + fo);
            f32x4 z = {};
            z = __builtin_amdgcn_mfma_f32_16x16x32_bf16(k0v, aq0, z, 0, 0, 0);
            z = __builtin_amdgcn_mfma_f32_16x16x32_bf16(k1v, aq1, z, 0, 0, 0);
            bf16x4 ev;
            #pragma unroll
            for (int r = 0; r < 4; ++r) {
                float val = __expf(z[r] * 0.125f);
                if (causal) {
                    if (kg + kf * 16 + cr + r > q0 + qw0 + fr) val = 0.f;
                }
                ev[r] = (bf16_t)val;
            }
            const int q = qw0 + fr;
            const int p = (kf * 2 + (fog >> 1)) ^ (fr & 7);
            *reinterpret_cast<bf16x4*>(ebuf + q * 64 + p * 8 + (fog & 1) * 4) = ev;
        }

        __syncthreads();   // e(t) visible

        // ---- cross-head normalize in place: 1024 threads x 2 elems ----
        {
            const int q = tid >> 5;          // 0..31
            const int j = tid & 31;          // k-pair index (k = 2j)
            const int p = (j >> 2) ^ (q & 7);
            bf16_t* base = &e_lds[t & 1][0][0][0] + q * 64 + p * 8 + (j & 3) * 2;
            float d0 = 0.f, d1 = 0.f;
            #pragma unroll
            for (int hh = 0; hh < NH; ++hh) {
                const bf16x2 v = *reinterpret_cast<const bf16x2*>(base + hh * (QT * 64));
                d0 += (float)v[0]; d1 += (float)v[1];
            }
            const float r0 = (d0 > 0.f) ? __builtin_amdgcn_rcpf(d0) : 0.f;
            const float r1 = (d1 > 0.f) ? __builtin_amdgcn_rcpf(d1) : 0.f;
            #pragma unroll
            for (int hh = 0; hh < NH; ++hh) {
                bf16_t* pp = base + hh * (QT * 64);
                const bf16x2 v = *reinterpret_cast<const bf16x2*>(pp);
                bf16x2 wv;
                wv[0] = (bf16_t)((float)v[0] * r0);
                wv[1] = (bf16_t)((float)v[1] * r1);
                *reinterpret_cast<bf16x2*>(pp) = wv;
            }
        }
        __syncthreads();   // w(t) ready

        // ---- PV(t): o += w(t) @ V(t) ----
        #pragma unroll 1
        for (int c = 0; c < 2; ++c) {
            const int q = qw0 + fr;
            const int p = (c * 4 + fog) ^ (fr & 7);
            const bf16x8 pa = *reinterpret_cast<const bf16x8*>(ebuf + q * 64 + p * 8);
            #pragma unroll
            for (int n = 0; n < 4; ++n) {
                const bf16x8 vvn = *reinterpret_cast<const bf16x8*>(
                    vtw + ((size_t)(h * DH + n * 16 + fr)) * S_LEN + kg + c * 32 + fo);
                o[n] = __builtin_amdgcn_mfma_f32_16x16x32_bf16(pa, vvn, o[n], 0, 0, 0);
            }
        }
        // next tile writes the other buffer; 2 barriers/tile total
    }

    // ---- write partial output tile: rows q0+qw0+cr+r, col h*64+n*16+fr ----
    bf16_t* pp = part + (size_t)kc * (S_LEN * DE);
    #pragma unroll
    for (int n = 0; n < 4; ++n)
        #pragma unroll
        for (int r = 0; r < 4; ++r)
            pp[(size_t)(q0 + qw0 + cr + r) * DE + h * 64 + n * 16 + fr] =
                (bf16_t)o[n][r];
}

// ---------------------------------------------------------------------------
// Kernel 3: out = (sum_kc part_kc) @ w_out^T + b_out   (f32 output)
// ---------------------------------------------------------------------------
template<int KS>
__global__ __launch_bounds__(256) void out_gemm(
    const bf16_t* __restrict__ part,   // [KS][4096][512] bf16
    const float*  __restrict__ Wout,
    const float*  __restrict__ bout,
    float* __restrict__ out)
{
    __shared__ bf16_t As[BM * LDP];
    __shared__ bf16_t Bs[BN * LDP];

    const int tid  = threadIdx.x;
    const int lane = tid & 63;
    const int w    = tid >> 6;
    const int wr   = w >> 1, wc = w & 1;
    const int row0 = blockIdx.y * BM;
    const int col0 = blockIdx.x * BN;

    const int fr = lane & 15;
    const int fo = (lane >> 4) * 8;
    const int cr = (lane >> 4) * 4;

    const int sr = tid >> 1;
    const int sc = (tid & 1) * 16;

    f32x4 acc[4][4] = {};

    for (int k0 = 0; k0 < DE; k0 += BK) {
        // A staging: sum KS partials (bf16 -> f32 add -> bf16)
        {
            const size_t off = (size_t)(row0 + sr) * DE + k0 + sc;
            #pragma unroll
            for (int v = 0; v < 2; ++v) {
                bf16x8 a = *reinterpret_cast<const bf16x8*>(part + off + v * 8);
                #pragma unroll
                for (int p = 1; p < KS; ++p) {
                    bf16x8 b = *reinterpret_cast<const bf16x8*>(
                        part + (size_t)p * (S_LEN * DE) + off + v * 8);
                    #pragma unroll
                    for (int j = 0; j < 8; ++j)
                        a[j] = (bf16_t)((float)a[j] + (float)b[j]);
                }
                *reinterpret_cast<bf16x8*>(As + sr * LDP + sc + v * 8) = a;
            }
        }
        stage16_f32(Bs + sr * LDP + sc, Wout + (col0 + sr) * DE + k0 + sc);
        __syncthreads();

        bf16x8 af[4], bf[4];
        #pragma unroll
        for (int m = 0; m < 4; ++m)
            af[m] = *reinterpret_cast<const bf16x8*>(As + (wr * 64 + m * 16 + fr) * LDP + fo);
        #pragma unroll
        for (int n = 0; n < 4; ++n)
            bf[n] = *reinterpret_cast<const bf16x8*>(Bs + (wc * 64 + n * 16 + fr) * LDP + fo);
        #pragma unroll
        for (int m = 0; m < 4; ++m)
            #pragma unroll
            for (int n = 0; n < 4; ++n)
                acc[m][n] = __builtin_amdgcn_mfma_f32_16x16x32_bf16(af[m], bf[n], acc[m][n], 0, 0, 0);
        __syncthreads();
    }

    #pragma unroll
    for (int m = 0; m < 4; ++m) {
        #pragma unroll
        for (int n = 0; n < 4; ++n) {
            const int col = col0 + wc * 64 + n * 16 + fr;
            const float b = bout[col];
            #pragma unroll
            for (int r = 0; r < 4; ++r) {
                const int row = row0 + wr * 64 + m * 16 + cr + r;
                out[row * DE + col] = acc[m][n][r] + b;
            }
        }
    }
}

// ---------------------------------------------------------------------------
// Launch: pick key-split factor by available workspace.
//   needs (3 + KS) * 4 MiB of d_ws.
// ---------------------------------------------------------------------------
extern "C" void kernel_launch(void* const* d_in, const int* in_sizes, int n_in,
                              void* d_out, int out_size, void* d_ws, size_t ws_size,
                              hipStream_t stream) {
    const float* x     = (const float*)d_in[0];
    const float* w_in  = (const float*)d_in[1];
    const float* b_in  = (const float*)d_in[2];
    const float* w_out = (const float*)d_in[3];
    const float* b_out = (const float*)d_in[4];
    const int*   causal = (const int*)d_in[5];
    float* out = (float*)d_out;

    const size_t segE = (size_t)NH * S_LEN * DH;      // 2M bf16 elems = 4 MiB
    bf16_t* qw   = (bf16_t*)d_ws;
    bf16_t* kw   = qw  + segE;
    bf16_t* vtw  = kw  + segE;
    bf16_t* part = vtw + segE;

    dim3 g1(3 * DE / BN, S_LEN / BM);   // (12, 32)
    qkv_gemm<<<g1, 256, 0, stream>>>(x, w_in, b_in, qw, kw, vtw);

    dim3 g3(DE / BN, S_LEN / BM);       // (4, 32)

    const size_t segB = segE * sizeof(bf16_t);        // 4 MiB
    if (ws_size >= 7 * segB) {
        // KS=4: grid = 4 * 128 = 512 blocks of 16 waves -> 2 blocks/CU
        attn_kernel<4><<<512, 1024, 0, stream>>>(qw, kw, vtw, causal, part);
        out_gemm<4><<<g3, 256, 0, stream>>>(part, w_out, b_out, out);
    } else if (ws_size >= 5 * segB) {
        attn_kernel<2><<<256, 1024, 0, stream>>>(qw, kw, vtw, causal, part);
        out_gemm<2><<<g3, 256, 0, stream>>>(part, w_out, b_out, out);
    } else {
        attn_kernel<1><<<128, 1024, 0, stream>>>(qw, kw, vtw, causal, part);
        out_gemm<1><<<g3, 256, 0, stream>>>(part, w_out, b_out, out);
    }
}

// Round 9
// 303.376 us; speedup vs baseline: 1.0676x; 1.0676x over previous
//
#include <hip/hip_runtime.h>
#include <hip/hip_bf16.h>

typedef __bf16 bf16_t;
typedef __bf16 bf16x8 __attribute__((ext_vector_type(8)));
typedef __bf16 bf16x4 __attribute__((ext_vector_type(4)));
typedef __bf16 bf16x2 __attribute__((ext_vector_type(2)));
typedef float  f32x4  __attribute__((ext_vector_type(4)));

#define S_LEN 4096
#define NH    8
#define DH    64
#define DE    512

// ---------------------------------------------------------------------------
// GEMM tile params (both projection GEMMs)
// ---------------------------------------------------------------------------
#define BM 128
#define BN 128
#define BK 32
#define LDP 40

static __device__ __forceinline__ void stage16_f32(bf16_t* dst, const float* src) {
    const float4 v0 = *reinterpret_cast<const float4*>(src + 0);
    const float4 v1 = *reinterpret_cast<const float4*>(src + 4);
    const float4 v2 = *reinterpret_cast<const float4*>(src + 8);
    const float4 v3 = *reinterpret_cast<const float4*>(src + 12);
    bf16x8 lo, hi;
    lo[0]=(bf16_t)v0.x; lo[1]=(bf16_t)v0.y; lo[2]=(bf16_t)v0.z; lo[3]=(bf16_t)v0.w;
    lo[4]=(bf16_t)v1.x; lo[5]=(bf16_t)v1.y; lo[6]=(bf16_t)v1.z; lo[7]=(bf16_t)v1.w;
    hi[0]=(bf16_t)v2.x; hi[1]=(bf16_t)v2.y; hi[2]=(bf16_t)v2.z; hi[3]=(bf16_t)v2.w;
    hi[4]=(bf16_t)v3.x; hi[5]=(bf16_t)v3.y; hi[6]=(bf16_t)v3.z; hi[7]=(bf16_t)v3.w;
    *reinterpret_cast<bf16x8*>(dst + 0) = lo;
    *reinterpret_cast<bf16x8*>(dst + 8) = hi;
}

// ---------------------------------------------------------------------------
// Kernel 1: qkv = x @ w_in^T + b_in ; scatter to Q [h][s][64], K [h][s][64],
//           V^T [h][64][s]   (all bf16)
// ---------------------------------------------------------------------------
__global__ __launch_bounds__(256) void qkv_gemm(
    const float* __restrict__ X,
    const float* __restrict__ Win,
    const float* __restrict__ bin,
    bf16_t* __restrict__ qw,
    bf16_t* __restrict__ kw,
    bf16_t* __restrict__ vtw)
{
    __shared__ bf16_t As[BM * LDP];
    __shared__ bf16_t Bs[BN * LDP];

    const int tid  = threadIdx.x;
    const int lane = tid & 63;
    const int w    = tid >> 6;
    const int wr   = w >> 1, wc = w & 1;
    const int row0 = blockIdx.y * BM;
    const int col0 = blockIdx.x * BN;

    const int fr = lane & 15;
    const int fo = (lane >> 4) * 8;
    const int cr = (lane >> 4) * 4;

    const int sr = tid >> 1;
    const int sc = (tid & 1) * 16;

    f32x4 acc[4][4] = {};

    for (int k0 = 0; k0 < DE; k0 += BK) {
        stage16_f32(As + sr * LDP + sc, X   + (row0 + sr) * DE + k0 + sc);
        stage16_f32(Bs + sr * LDP + sc, Win + (col0 + sr) * DE + k0 + sc);
        __syncthreads();

        bf16x8 af[4], bf[4];
        #pragma unroll
        for (int m = 0; m < 4; ++m)
            af[m] = *reinterpret_cast<const bf16x8*>(As + (wr * 64 + m * 16 + fr) * LDP + fo);
        #pragma unroll
        for (int n = 0; n < 4; ++n)
            bf[n] = *reinterpret_cast<const bf16x8*>(Bs + (wc * 64 + n * 16 + fr) * LDP + fo);
        #pragma unroll
        for (int m = 0; m < 4; ++m)
            #pragma unroll
            for (int n = 0; n < 4; ++n)
                acc[m][n] = __builtin_amdgcn_mfma_f32_16x16x32_bf16(af[m], bf[n], acc[m][n], 0, 0, 0);
        __syncthreads();
    }

    #pragma unroll
    for (int m = 0; m < 4; ++m) {
        #pragma unroll
        for (int n = 0; n < 4; ++n) {
            const int col = col0 + wc * 64 + n * 16 + fr;
            const float b = bin[col];
            const int part = col >> 9;
            const int cd   = col & 511;
            const int h    = cd >> 6;
            const int d    = cd & 63;
            #pragma unroll
            for (int r = 0; r < 4; ++r) {
                const int row = row0 + wr * 64 + m * 16 + cr + r;
                const float v = acc[m][n][r] + b;
                const bf16_t bv = (bf16_t)v;
                if (part == 0)      qw [(h * S_LEN + row) * DH + d] = bv;
                else if (part == 1) kw [(h * S_LEN + row) * DH + d] = bv;
                else                vtw[(h * DH + d) * S_LEN + row] = bv;
            }
        }
    }
}

// ---------------------------------------------------------------------------
// Kernel 2: attention, softmax over HEADS axis.
// 512-thread block = 8 waves = 8 heads (the geometry that worked in r7),
// QT=16 queries/block, KS-way key split. Double-buffered e-LDS is now only
// 32 KB -> 4 blocks/CU = 32 waves/CU; grid = KS*256 = 1024 = exactly 4/CU.
// kc = blockIdx&3 with XCD = blockIdx%8 -> each XCD touches ONE 2 MB K+V
// slice (L2-resident).
//
// Transposed QK^T (r8's store fix, in the safe geometry): mfma(K,Q) ->
// D[col=q=fr, row=k=cr+r] -> lane holds 4 consecutive k for fixed q -> one
// b64 e-store per kf (r7 needed 16 scalar b16 stores/tile). 16B-block XOR
// swizzle p' = p ^ (q&7); all accesses 2-way max (free). PV pa-read is
// r7's verified pattern unchanged.
//
// Register budget: __launch_bounds__(512,8) -> 64 unified regs/wave for
// 8 waves/SIMD. Demand: aq 8 + kfrag 8 + z 4 + o 16 (acc) + temps ~ 50.
// unroll 1 on kf/c loops prevents hoisting past the budget.
// ---------------------------------------------------------------------------
template<int KS>
__global__ __launch_bounds__(512, 8) void attn_kernel(
    const bf16_t* __restrict__ qw,    // [h][s][64]
    const bf16_t* __restrict__ kw,    // [h][s][64]
    const bf16_t* __restrict__ vtw,   // [h][64][s]
    const int*    __restrict__ causal_p,
    bf16_t* __restrict__ part)        // [KS][s][512] partial outputs
{
    constexpr int QT = 16;
    constexpr int NT = (S_LEN / KS) / 64;
    constexpr int KSH = (KS == 4) ? 2 : (KS == 2 ? 1 : 0);

    __shared__ bf16_t e_lds[2][NH][QT][64];   // 32 KB

    const int tid  = threadIdx.x;
    const int lane = tid & 63;
    const int h    = tid >> 6;          // wave = head
    const int kc   = blockIdx.x & (KS - 1);
    const int q0   = (blockIdx.x >> KSH) * QT;
    const int kbase = kc * (S_LEN / KS);
    const int causal = causal_p[0];

    const int fr  = lane & 15;
    const int fog = lane >> 4;
    const int fo  = fog * 8;
    const int cr  = fog * 4;

    // Q fragment (B-operand of transposed QK^T; also same data layout as
    // r7's A-operand): lane fr holds Q[q0+fr][d = fo..fo+7 (+32)]
    bf16x8 aq0, aq1;
    {
        const bf16_t* qb = qw + ((size_t)(h * S_LEN) + q0 + fr) * DH;
        aq0 = *reinterpret_cast<const bf16x8*>(qb + fo);
        aq1 = *reinterpret_cast<const bf16x8*>(qb + 32 + fo);
    }

    f32x4 o[4] = {};   // output accumulators (acc regs)

    for (int t = 0; t < NT; ++t) {
        const int kg = kbase + t * 64;
        bf16_t* ebuf = &e_lds[t & 1][h][0][0];

        // ---- transposed QK^T + exp: D[k][q], one b64 e-write per kf ----
        #pragma unroll 1
        for (int kf = 0; kf < 4; ++kf) {
            const bf16_t* kb = kw + ((size_t)(h * S_LEN) + kg + kf * 16 + fr) * DH;
            const bf16x8 k0v = *reinterpret_cast<const bf16x8*>(kb + fo);
            const bf16x8 k1v = *reinterpret_cast<const bf16x8*>(kb + 32 + fo);
            f32x4 z = {};
            z = __builtin_amdgcn_mfma_f32_16x16x32_bf16(k0v, aq0, z, 0, 0, 0);
            z = __builtin_amdgcn_mfma_f32_16x16x32_bf16(k1v, aq1, z, 0, 0, 0);
            bf16x4 ev;
            #pragma unroll
            for (int r = 0; r < 4; ++r) {
                float val = __expf(z[r] * 0.125f);
                if (causal) {
                    if (kg + kf * 16 + cr + r > q0 + fr) val = 0.f;
                }
                ev[r] = (bf16_t)val;
            }
            // k_local = kf*16 + cr + r ; q = fr ; 16B-block swizzle ^ (q&7)
            const int p = (kf * 2 + (fog >> 1)) ^ (fr & 7);
            *reinterpret_cast<bf16x4*>(ebuf + fr * 64 + p * 8 + (fog & 1) * 4) = ev;
        }

        __syncthreads();   // e(t) visible

        // ---- cross-head normalize in place: 512 threads x 2 elems ----
        {
            const int q = tid >> 5;          // 0..15
            const int j = tid & 31;          // k-pair index (k = 2j)
            const int p = (j >> 2) ^ (q & 7);
            bf16_t* base = &e_lds[t & 1][0][0][0] + q * 64 + p * 8 + (j & 3) * 2;
            float d0 = 0.f, d1 = 0.f;
            #pragma unroll 2
            for (int hh = 0; hh < NH; ++hh) {
                const bf16x2 v = *reinterpret_cast<const bf16x2*>(base + hh * (QT * 64));
                d0 += (float)v[0]; d1 += (float)v[1];
            }
            const float r0 = (d0 > 0.f) ? __builtin_amdgcn_rcpf(d0) : 0.f;
            const float r1 = (d1 > 0.f) ? __builtin_amdgcn_rcpf(d1) : 0.f;
            #pragma unroll 2
            for (int hh = 0; hh < NH; ++hh) {
                bf16_t* pp = base + hh * (QT * 64);
                const bf16x2 v = *reinterpret_cast<const bf16x2*>(pp);
                bf16x2 wv;
                wv[0] = (bf16_t)((float)v[0] * r0);
                wv[1] = (bf16_t)((float)v[1] * r1);
                *reinterpret_cast<bf16x2*>(pp) = wv;
            }
        }
        __syncthreads();   // w(t) ready

        // ---- PV(t): o += w(t) @ V(t) ----
        #pragma unroll 1
        for (int c = 0; c < 2; ++c) {
            const int p = (c * 4 + fog) ^ (fr & 7);
            const bf16x8 pa = *reinterpret_cast<const bf16x8*>(ebuf + fr * 64 + p * 8);
            #pragma unroll
            for (int n = 0; n < 4; ++n) {
                const bf16x8 vvn = *reinterpret_cast<const bf16x8*>(
                    vtw + ((size_t)(h * DH + n * 16 + fr)) * S_LEN + kg + c * 32 + fo);
                o[n] = __builtin_amdgcn_mfma_f32_16x16x32_bf16(pa, vvn, o[n], 0, 0, 0);
            }
        }
        // next tile writes the other buffer; 2 barriers/tile total
    }

    // ---- write partial output tile: rows q0+cr+r, col h*64+n*16+fr ----
    bf16_t* pp = part + (size_t)kc * (S_LEN * DE);
    #pragma unroll
    for (int n = 0; n < 4; ++n)
        #pragma unroll
        for (int r = 0; r < 4; ++r)
            pp[(size_t)(q0 + cr + r) * DE + h * 64 + n * 16 + fr] =
                (bf16_t)o[n][r];
}

// ---------------------------------------------------------------------------
// Kernel 3: out = (sum_kc part_kc) @ w_out^T + b_out   (f32 output)
// ---------------------------------------------------------------------------
template<int KS>
__global__ __launch_bounds__(256) void out_gemm(
    const bf16_t* __restrict__ part,   // [KS][4096][512] bf16
    const float*  __restrict__ Wout,
    const float*  __restrict__ bout,
    float* __restrict__ out)
{
    __shared__ bf16_t As[BM * LDP];
    __shared__ bf16_t Bs[BN * LDP];

    const int tid  = threadIdx.x;
    const int lane = tid & 63;
    const int w    = tid >> 6;
    const int wr   = w >> 1, wc = w & 1;
    const int row0 = blockIdx.y * BM;
    const int col0 = blockIdx.x * BN;

    const int fr = lane & 15;
    const int fo = (lane >> 4) * 8;
    const int cr = (lane >> 4) * 4;

    const int sr = tid >> 1;
    const int sc = (tid & 1) * 16;

    f32x4 acc[4][4] = {};

    for (int k0 = 0; k0 < DE; k0 += BK) {
        // A staging: sum KS partials (bf16 -> f32 add -> bf16)
        {
            const size_t off = (size_t)(row0 + sr) * DE + k0 + sc;
            #pragma unroll
            for (int v = 0; v < 2; ++v) {
                bf16x8 a = *reinterpret_cast<const bf16x8*>(part + off + v * 8);
                #pragma unroll
                for (int p = 1; p < KS; ++p) {
                    bf16x8 b = *reinterpret_cast<const bf16x8*>(
                        part + (size_t)p * (S_LEN * DE) + off + v * 8);
                    #pragma unroll
                    for (int j = 0; j < 8; ++j)
                        a[j] = (bf16_t)((float)a[j] + (float)b[j]);
                }
                *reinterpret_cast<bf16x8*>(As + sr * LDP + sc + v * 8) = a;
            }
        }
        stage16_f32(Bs + sr * LDP + sc, Wout + (col0 + sr) * DE + k0 + sc);
        __syncthreads();

        bf16x8 af[4], bf[4];
        #pragma unroll
        for (int m = 0; m < 4; ++m)
            af[m] = *reinterpret_cast<const bf16x8*>(As + (wr * 64 + m * 16 + fr) * LDP + fo);
        #pragma unroll
        for (int n = 0; n < 4; ++n)
            bf[n] = *reinterpret_cast<const bf16x8*>(Bs + (wc * 64 + n * 16 + fr) * LDP + fo);
        #pragma unroll
        for (int m = 0; m < 4; ++m)
            #pragma unroll
            for (int n = 0; n < 4; ++n)
                acc[m][n] = __builtin_amdgcn_mfma_f32_16x16x32_bf16(af[m], bf[n], acc[m][n], 0, 0, 0);
        __syncthreads();
    }

    #pragma unroll
    for (int m = 0; m < 4; ++m) {
        #pragma unroll
        for (int n = 0; n < 4; ++n) {
            const int col = col0 + wc * 64 + n * 16 + fr;
            const float b = bout[col];
            #pragma unroll
            for (int r = 0; r < 4; ++r) {
                const int row = row0 + wr * 64 + m * 16 + cr + r;
                out[row * DE + col] = acc[m][n][r] + b;
            }
        }
    }
}

// ---------------------------------------------------------------------------
// Launch: pick key-split factor by available workspace.
//   needs (3 + KS) * 4 MiB of d_ws.
// ---------------------------------------------------------------------------
extern "C" void kernel_launch(void* const* d_in, const int* in_sizes, int n_in,
                              void* d_out, int out_size, void* d_ws, size_t ws_size,
                              hipStream_t stream) {
    const float* x     = (const float*)d_in[0];
    const float* w_in  = (const float*)d_in[1];
    const float* b_in  = (const float*)d_in[2];
    const float* w_out = (const float*)d_in[3];
    const float* b_out = (const float*)d_in[4];
    const int*   causal = (const int*)d_in[5];
    float* out = (float*)d_out;

    const size_t segE = (size_t)NH * S_LEN * DH;      // 2M bf16 elems = 4 MiB
    bf16_t* qw   = (bf16_t*)d_ws;
    bf16_t* kw   = qw  + segE;
    bf16_t* vtw  = kw  + segE;
    bf16_t* part = vtw + segE;

    dim3 g1(3 * DE / BN, S_LEN / BM);   // (12, 32)
    qkv_gemm<<<g1, 256, 0, stream>>>(x, w_in, b_in, qw, kw, vtw);

    dim3 g3(DE / BN, S_LEN / BM);       // (4, 32)

    const size_t segB = segE * sizeof(bf16_t);        // 4 MiB
    if (ws_size >= 7 * segB) {
        // QT=16, KS=4: grid = 4 * 256 = 1024 blocks -> exactly 4/CU
        attn_kernel<4><<<1024, 512, 0, stream>>>(qw, kw, vtw, causal, part);
        out_gemm<4><<<g3, 256, 0, stream>>>(part, w_out, b_out, out);
    } else if (ws_size >= 5 * segB) {
        attn_kernel<2><<<512, 512, 0, stream>>>(qw, kw, vtw, causal, part);
        out_gemm<2><<<g3, 256, 0, stream>>>(part, w_out, b_out, out);
    } else {
        attn_kernel<1><<<256, 512, 0, stream>>>(qw, kw, vtw, causal, part);
        out_gemm<1><<<g3, 256, 0, stream>>>(part, w_out, b_out, out);
    }
}